// Round 5
// baseline (117.448 us; speedup 1.0000x reference)
//
#include <hip/hip_runtime.h>

// Problem constants (fixed by reference setup_inputs)
namespace {
constexpr int B_  = 4;
constexpr int C_  = 64;
constexpr int N_  = 16384;
constexpr int K_  = 16;
constexpr int R3_ = 4096;   // 16^3

// workspace layout (in floats)
constexpr int OFF_MEANS = 0;                        // 12 (pad 16)
constexpr int OFF_XT    = 16;                       // bf16 [B,N,C]   (B*N*C/2 floats)
constexpr int OFF_PTS   = OFF_XT  + B_*N_*C_/2;     // f32  [B,N,8] {xyz, hproj, 0,0}
constexpr int OFF_VOX2  = OFF_PTS + B_*N_*8;        // bf16 [B,R3,C]  (B*R3*C/2 floats)
}

__device__ __forceinline__ unsigned short f2bf(float f) {
  unsigned u = __float_as_uint(f);
  return (unsigned short)((u + 0x7FFFu + ((u >> 16) & 1u)) >> 16);   // RNE
}
__device__ __forceinline__ float bf2f(unsigned short h) {
  return __uint_as_float(((unsigned)h) << 16);
}
__device__ __forceinline__ unsigned cvtpk_bf16(float lo, float hi) {
  unsigned r;
  asm("v_cvt_pk_bf16_f32 %0, %1, %2" : "=v"(r) : "v"(lo), "v"(hi));
  return r;
}

// ---------------------------------------------------------------------------
// Kernel 1: per-(batch,axis) fp64 mean of xyz. 12 blocks.
// ---------------------------------------------------------------------------
__global__ __launch_bounds__(256) void k_init(
    const float* __restrict__ xyz, float* __restrict__ means) {
  __shared__ double red[256];
  const int blk = blockIdx.x;           // b*3 + axis
  const float* p = xyz + blk * N_;
  double s = 0.0;
  for (int i = threadIdx.x; i < N_; i += 256) s += (double)p[i];
  red[threadIdx.x] = s;
  __syncthreads();
  for (int st = 128; st; st >>= 1) {
    if (threadIdx.x < st) red[threadIdx.x] += red[threadIdx.x + st];
    __syncthreads();
  }
  if (threadIdx.x == 0) means[blk] = (float)(red[0] * (1.0 / (double)N_));
}

// ---------------------------------------------------------------------------
// Kernel 2: per 64-point tile — transpose x -> xT bf16 [B,N,C], hproj (3xC
// matvec), pack pts8 {xyz, hproj, 0, 0} with coalesced float4 writes.
// No atomics, no means dependency. grid = B*N/64, block = 256.
// ---------------------------------------------------------------------------
__global__ __launch_bounds__(256) void k_prep(
    const float* __restrict__ x, const float* __restrict__ xyz,
    const float* __restrict__ pw1,
    unsigned short* __restrict__ xT, float* __restrict__ pts) {
  __shared__ float tile[64 * 65];
  __shared__ float xyzs[3][64];
  __shared__ float hp[3][64];

  const int t   = threadIdx.x;
  const int blk = blockIdx.x;
  const int b   = blk >> 8;          // 256 tiles per batch
  const int n0  = (blk & 255) << 6;

  // load x tile [c=64][n=64], coalesced rows
#pragma unroll
  for (int i = 0; i < 16; ++i) {
    int c = i * 4 + (t >> 6);
    int j = t & 63;
    tile[c * 65 + j] = x[((size_t)(b * C_ + c)) * N_ + n0 + j];
  }
  if (t < 192) {
    int p = t & 63, q = t >> 6;
    xyzs[q][p] = xyz[((size_t)(b * 3 + q)) * N_ + n0 + p];
  }
  __syncthreads();

  // transposed bf16 write, coalesced in c (128B/wave)
#pragma unroll
  for (int i = 0; i < 16; ++i) {
    int p = i * 4 + (t >> 6);
    int c = t & 63;
    xT[((size_t)(b * N_ + n0 + p)) * C_ + c] = f2bf(tile[c * 65 + p]);
  }

  // hproj (3 waves: q = proj row, lane = point)
  if (t < 192) {
    int p = t & 63, q = t >> 6;
    float s = 0.f;
#pragma unroll
    for (int c = 0; c < 64; ++c) s = fmaf(pw1[q * 64 + c], tile[c * 65 + p], s);
    hp[q][p] = s;
  }
  __syncthreads();

  // coalesced pts pack: threads 0-127 write one float4 each
  if (t < 128) {
    const int p = t >> 1;
    float4 v;
    if (t & 1) v = make_float4(hp[1][p], hp[2][p], 0.f, 0.f);
    else       v = make_float4(xyzs[0][p], xyzs[1][p], xyzs[2][p], hp[0][p]);
    *(float4*)(pts + ((size_t)(b * N_ + n0 + p)) * 8 + (t & 1) * 4) = v;
  }
}

// ---------------------------------------------------------------------------
// Kernel 3 (FUSED voxelize + conv): one block per (b,c). LDS-privatized
// cnt/sum over all 16384 points (LDS atomics; no global accumulators, no
// zero-fill kernel, no uncoalesced column reads), then divide + pad +
// depthwise conv3d x2 with folded bias+BN+LeakyReLU -> vox2 bf16 [vox][c].
// ---------------------------------------------------------------------------
__global__ __launch_bounds__(256) void k_voxconv(
    const float* __restrict__ x, const float* __restrict__ xyz,
    const float* __restrict__ means,
    const float* __restrict__ w3d1, const float* __restrict__ b3d1,
    const float* __restrict__ bn1, const float* __restrict__ w3d2,
    const float* __restrict__ b3d2, const float* __restrict__ bn2,
    unsigned short* __restrict__ vox2) {
  __shared__ float cnt_s[R3_];
  __shared__ float sum_s[R3_];
  __shared__ float va[18 * 18 * 18];
  __shared__ float vb[18 * 18 * 18];
  const int t = threadIdx.x;
  const int b = blockIdx.x >> 6;
  const int c = blockIdx.x & 63;

  // zero LDS accumulators + padded conv buffers
#pragma unroll
  for (int i = 0; i < 16; ++i) { cnt_s[t + i * 256] = 0.f; sum_s[t + i * 256] = 0.f; }
  for (int i = t; i < 18 * 18 * 18; i += 256) { va[i] = 0.f; vb[i] = 0.f; }

  float W1[27], W2[27];
#pragma unroll
  for (int i = 0; i < 27; ++i) { W1[i] = w3d1[c * 27 + i]; W2[i] = w3d2[c * 27 + i]; }
  const float s1 = bn1[c] / sqrtf(bn1[192 + c] + 1e-4f);
  const float d1 = (b3d1[c] - bn1[128 + c]) * s1 + bn1[64 + c];
  const float s2 = bn2[c] / sqrtf(bn2[192 + c] + 1e-4f);
  const float d2 = (b3d2[c] - bn2[128 + c]) * s2 + bn2[64 + c];

  const float m0 = means[b * 3 + 0], m1 = means[b * 3 + 1], m2 = means[b * 3 + 2];
  const float* __restrict__ xr  = x   + ((size_t)(b * C_ + c)) * N_;
  const float* __restrict__ xy0 = xyz + ((size_t)(b * 3 + 0)) * N_;
  const float* __restrict__ xy1 = xyz + ((size_t)(b * 3 + 1)) * N_;
  const float* __restrict__ xy2 = xyz + ((size_t)(b * 3 + 2)) * N_;
  __syncthreads();

  // accumulate: 64 points per thread, coalesced streams + LDS atomics
#pragma unroll 4
  for (int i = 0; i < 64; ++i) {
    const int n = t + i * 256;
    const float xv = xr[n];
    const float a0 = xy0[n], a1 = xy1[n], a2 = xy2[n];
    const int vx = (int)rintf(fminf(fmaxf((a0 - m0 + 1.0f) * 8.0f, 0.0f), 15.0f));
    const int vy = (int)rintf(fminf(fmaxf((a1 - m1 + 1.0f) * 8.0f, 0.0f), 15.0f));
    const int vz = (int)rintf(fminf(fmaxf((a2 - m2 + 1.0f) * 8.0f, 0.0f), 15.0f));
    const int f = (vx * 16 + vy) * 16 + vz;
    atomicAdd(&cnt_s[f], 1.0f);
    atomicAdd(&sum_s[f], xv);
  }
  __syncthreads();

  // divide + pad into va interior
#pragma unroll
  for (int i = 0; i < 16; ++i) {
    int vox = t + i * 256;
    int z = vox & 15, y = (vox >> 4) & 15, xx = vox >> 8;
    va[((xx + 1) * 18 + (y + 1)) * 18 + (z + 1)] =
        sum_s[vox] / fmaxf(cnt_s[vox], 1.0f);
  }
  __syncthreads();

  // conv1 + bias + BN + leaky(0.1)
#pragma unroll
  for (int i = 0; i < 16; ++i) {
    int vox = t + i * 256;
    int z = vox & 15, y = (vox >> 4) & 15, xx = vox >> 8;
    int base = ((xx + 1) * 18 + (y + 1)) * 18 + (z + 1);
    float acc = 0.f;
#pragma unroll
    for (int dx = -1; dx <= 1; ++dx)
#pragma unroll
      for (int dy = -1; dy <= 1; ++dy)
#pragma unroll
        for (int dz = -1; dz <= 1; ++dz)
          acc = fmaf(W1[((dx + 1) * 3 + (dy + 1)) * 3 + (dz + 1)],
                     va[base + dx * 324 + dy * 18 + dz], acc);
    float tt = acc * s1 + d1;
    vb[base] = tt > 0.f ? tt : 0.1f * tt;
  }
  __syncthreads();

  // conv2 + bias + BN + leaky(0.1) -> vox2 [b][vox][c] bf16
#pragma unroll
  for (int i = 0; i < 16; ++i) {
    int vox = t + i * 256;
    int z = vox & 15, y = (vox >> 4) & 15, xx = vox >> 8;
    int base = ((xx + 1) * 18 + (y + 1)) * 18 + (z + 1);
    float acc = 0.f;
#pragma unroll
    for (int dx = -1; dx <= 1; ++dx)
#pragma unroll
      for (int dy = -1; dy <= 1; ++dy)
#pragma unroll
        for (int dz = -1; dz <= 1; ++dz)
          acc = fmaf(W2[((dx + 1) * 3 + (dy + 1)) * 3 + (dz + 1)],
                     vb[base + dx * 324 + dy * 18 + dz], acc);
    float tt = acc * s2 + d2;
    vox2[((size_t)(b * R3_ + vox)) * C_ + c] = f2bf(tt > 0.f ? tt : 0.1f * tt);
  }
}

// ---------------------------------------------------------------------------
// Kernel 4: fused trilinear devoxelize + point branch + add. Two phases:
//  A) 512 (p,k) pairs: 6 distinct weights computed once per pair, bf16 in LDS.
//  B) wave=point, lane=channel: slim max-pool loop + devox from precomputed
//     packed corners. grid = B*N/32 = 2048 blocks. XCD batch-affinity swizzle.
// ---------------------------------------------------------------------------
__global__ __launch_bounds__(256, 8) void k_final(
    const unsigned short* __restrict__ xT, const float* __restrict__ pts,
    const unsigned short* __restrict__ vox2, const int* __restrict__ idx,
    const float* __restrict__ means, const float* __restrict__ pbn,
    const float* __restrict__ pw2, const float* __restrict__ ptbn,
    float* __restrict__ out) {
  __shared__ unsigned w6[3][513];   // [dword][pair] packed 2xbf16 (513: bank-skew)
  __shared__ int      jarr[512];
  __shared__ unsigned dv[32][8];    // (corner voxidx << 16) | bf16(weight)
  __shared__ float    outT[64 * 33];

  const int t = threadIdx.x;
  const int blk = blockIdx.x;
  const int xcd = blk & 7;
  const int b = xcd >> 1;                          // XCD pair -> batch
  const int t32 = ((blk >> 3) << 1) | (xcd & 1);   // tile in [0,512)
  const int n0 = t32 * 32;

  // folded proj BN (3ch) + W2 — used by phase A
  const float psc0 = pbn[0] * rsqrtf(pbn[9]  + 1e-5f);
  const float psc1 = pbn[1] * rsqrtf(pbn[10] + 1e-5f);
  const float psc2 = pbn[2] * rsqrtf(pbn[11] + 1e-5f);
  const float pof0 = pbn[3] - pbn[6] * psc0;
  const float pof1 = pbn[4] - pbn[7] * psc1;
  const float pof2 = pbn[5] - pbn[8] * psc2;
  float W2r[9];
#pragma unroll
  for (int i = 0; i < 9; ++i) W2r[i] = pw2[i];

  const float* __restrict__ ptsb = pts + (size_t)b * N_ * 8;

  // ---------------- phase A: 512 pairs, 2 per thread ----------------
#pragma unroll
  for (int rep = 0; rep < 2; ++rep) {
    const int q = t + rep * 256;        // pair id = p*16 + k
    const int p = q >> 4;
    const int n = n0 + p;
    const int j = idx[(size_t)b * N_ * K_ + (size_t)n0 * K_ + q];
    jarr[q] = j;
    const float* qr = ptsb + (size_t)j * 8;
    float4 qa = *(const float4*)qr;
    float4 qb = *(const float4*)(qr + 4);
    const float* ir = ptsb + (size_t)n * 8;
    float4 pa = *(const float4*)ir;
    float4 pb = *(const float4*)(ir + 4);
    float d0 = qa.x - pa.x, d1 = qa.y - pa.y, d2 = qa.z - pa.z;
    float c0 = pof0 - psc0 * pa.w;
    float c1 = pof1 - psc1 * pb.x;
    float c2 = pof2 - psc2 * pb.y;
    float h0 = fmaxf(fmaf(qa.w, psc0, c0), 0.f);
    float h1 = fmaxf(fmaf(qb.x, psc1, c1), 0.f);
    float h2 = fmaxf(fmaf(qb.y, psc2, c2), 0.f);
    float e0 = fmaf(W2r[0], h0, fmaf(W2r[1], h1, W2r[2] * h2));
    float e1 = fmaf(W2r[3], h0, fmaf(W2r[4], h1, W2r[5] * h2));
    float e2 = fmaf(W2r[6], h0, fmaf(W2r[7], h1, W2r[8] * h2));
    w6[0][q] = cvtpk_bf16(d0, d1);
    w6[1][q] = cvtpk_bf16(d2, e0);
    w6[2][q] = cvtpk_bf16(e1, e2);
  }

  // devox precompute: threads 0-31, one point each
  if (t < 32) {
    const int n = n0 + t;
    const float* ir = ptsb + (size_t)n * 8;
    float x0 = ir[0], x1 = ir[1], x2 = ir[2];
    float nc0 = fminf(fmaxf((x0 - means[b * 3 + 0] + 1.0f) * 8.0f, 0.0f), 15.0f);
    float nc1 = fminf(fmaxf((x1 - means[b * 3 + 1] + 1.0f) * 8.0f, 0.0f), 15.0f);
    float nc2 = fminf(fmaxf((x2 - means[b * 3 + 2] + 1.0f) * 8.0f, 0.0f), 15.0f);
    int lx = (int)nc0, ly = (int)nc1, lz = (int)nc2;
    float fx = nc0 - (float)lx, fy = nc1 - (float)ly, fz = nc2 - (float)lz;
    int hx = lx < 15 ? lx + 1 : 15;
    int hy = ly < 15 ? ly + 1 : 15;
    int hz = lz < 15 ? lz + 1 : 15;
    float wx[2] = {1.f - fx, fx};
    float wy[2] = {1.f - fy, fy};
    float wz[2] = {1.f - fz, fz};
    int xi[2] = {lx, hx}, yi[2] = {ly, hy}, zi[2] = {lz, hz};
#pragma unroll
    for (int c8 = 0; c8 < 8; ++c8) {
      int dx = c8 >> 2, dy = (c8 >> 1) & 1, dz = c8 & 1;
      int flat = (xi[dx] * 16 + yi[dy]) * 16 + zi[dz];
      float wt = wx[dx] * wy[dy] * wz[dz];
      dv[t][c8] = ((unsigned)flat << 16) | (unsigned)f2bf(wt);
    }
  }
  __syncthreads();

  // ---------------- phase B: wave = point, lane = channel ----------------
  const int w = t >> 6, lane = t & 63;
  // lane's group: 0-9->d0, 10-19->d1, 20-29->d2, 30-39->e0, 40-49->e1, 50-63->e2
  const int widx = lane < 20 ? 0 : lane < 40 ? 1 : 2;
  const bool hi = (lane >= 10 && lane < 20) || (lane >= 30 && lane < 40) || (lane >= 50);
  const float ts = ptbn[lane] * rsqrtf(ptbn[192 + lane] + 1e-5f);
  const float td = ptbn[64 + lane] - ptbn[128 + lane] * ts;
  const unsigned short* __restrict__ xTb = xT + (size_t)b * N_ * C_;
  const unsigned short* __restrict__ voxb = vox2 + (size_t)b * R3_ * C_;

#pragma unroll
  for (int i = 0; i < 8; ++i) {
    const int p = i * 4 + w;

    // devox: 8 precomputed packed corners (broadcast LDS reads)
    float acc = 0.f;
#pragma unroll
    for (int c8 = 0; c8 < 8; ++c8) {
      unsigned dvv = dv[p][c8];
      float wt = __uint_as_float(dvv << 16);
      acc = fmaf(wt, bf2f(voxb[(size_t)(dvv >> 16) * C_ + lane]), acc);
    }

    // neighbor max-pool
    float pm = 0.f;   // relu folded: max_k relu(t) == max(0, max_k t)
    const unsigned* w6p = &w6[widx][p * 16];
#pragma unroll
    for (int k = 0; k < 16; ++k) {
      const int j = jarr[p * 16 + k];                        // broadcast
      const unsigned short xj = xTb[(size_t)j * C_ + lane];  // gather
      const unsigned wvp = w6p[k];                           // broadcast
      float wf = hi ? __uint_as_float(wvp & 0xffff0000u)
                    : __uint_as_float(wvp << 16);
      float v = bf2f(xj) * wf;
      pm = fmaxf(pm, fmaf(v, ts, td));
    }

    outT[lane * 33 + p] = acc + pm;
  }
  __syncthreads();

  // coalesced store: out[b][c][n0..n0+31]
#pragma unroll
  for (int i = 0; i < 8; ++i) {
    int c = i * 8 + (t >> 5);
    int col = t & 31;
    out[((size_t)(b * C_ + c)) * N_ + n0 + col] = outT[c * 33 + col];
  }
}

// ---------------------------------------------------------------------------
extern "C" void kernel_launch(void* const* d_in, const int* in_sizes, int n_in,
                              void* d_out, int out_size, void* d_ws, size_t ws_size,
                              hipStream_t stream) {
  const float* x     = (const float*)d_in[0];
  const float* xyz   = (const float*)d_in[1];
  const int*   idx   = (const int*)  d_in[2];
  const float* w3d1  = (const float*)d_in[3];
  const float* b3d1  = (const float*)d_in[4];
  const float* bn3d1 = (const float*)d_in[5];
  const float* w3d2  = (const float*)d_in[6];
  const float* b3d2  = (const float*)d_in[7];
  const float* bn3d2 = (const float*)d_in[8];
  const float* pw1   = (const float*)d_in[9];
  const float* pbn   = (const float*)d_in[10];
  const float* pw2   = (const float*)d_in[11];
  const float* ptbn  = (const float*)d_in[12];
  float* out = (float*)d_out;
  float* ws  = (float*)d_ws;

  k_init<<<dim3(12), dim3(256), 0, stream>>>(xyz, ws + OFF_MEANS);
  k_prep<<<dim3(B_ * N_ / 64), dim3(256), 0, stream>>>(
      x, xyz, pw1, (unsigned short*)(ws + OFF_XT), ws + OFF_PTS);
  k_voxconv<<<dim3(B_ * C_), dim3(256), 0, stream>>>(
      x, xyz, ws + OFF_MEANS, w3d1, b3d1, bn3d1, w3d2, b3d2, bn3d2,
      (unsigned short*)(ws + OFF_VOX2));
  k_final<<<dim3(B_ * N_ / 32), dim3(256), 0, stream>>>(
      (const unsigned short*)(ws + OFF_XT), ws + OFF_PTS,
      (const unsigned short*)(ws + OFF_VOX2), idx, ws + OFF_MEANS,
      pbn, pw2, ptbn, out);
}

// Round 6
// 90.073 us; speedup vs baseline: 1.3039x; 1.3039x over previous
//
#include <hip/hip_runtime.h>

// Problem constants (fixed by reference setup_inputs)
namespace {
constexpr int B_  = 4;
constexpr int C_  = 64;
constexpr int N_  = 16384;
constexpr int K_  = 16;
constexpr int R3_ = 4096;   // 16^3

// workspace layout (in floats)
constexpr int OFF_MEANS = 0;                        // 12 (pad 16)
constexpr int OFF_XT    = 16;                       // bf16 [B,N,C]   (B*N*C/2 floats)
constexpr int OFF_PTS   = OFF_XT  + B_*N_*C_/2;     // f32  [B,N,8] {xyz, hproj, 0,0}
constexpr int OFF_SUMS  = OFF_PTS + B_*N_*8;        // f32  [B,R3,C]
constexpr int OFF_CNTS  = OFF_SUMS + B_*R3_*C_;     // f32  [B,R3]
constexpr int OFF_VT    = OFF_CNTS + B_*R3_;        // f32  [B,C,R3]  (transposed mean)
constexpr int OFF_VOX2  = OFF_VT   + B_*C_*R3_;     // bf16 [B,R3,C]  (B*R3*C/2 floats)
constexpr int FILL_FLOATS = B_*R3_*C_ + B_*R3_;     // sums + cnts, contiguous
constexpr int FILL_BLOCKS = FILL_FLOATS / (256 * 4);  // = 1040 exactly
}

__device__ __forceinline__ unsigned short f2bf(float f) {
  unsigned u = __float_as_uint(f);
  return (unsigned short)((u + 0x7FFFu + ((u >> 16) & 1u)) >> 16);   // RNE
}
__device__ __forceinline__ float bf2f(unsigned short h) {
  return __uint_as_float(((unsigned)h) << 16);
}
__device__ __forceinline__ unsigned cvtpk_bf16(float lo, float hi) {
  unsigned r;
  asm("v_cvt_pk_bf16_f32 %0, %1, %2" : "=v"(r) : "v"(lo), "v"(hi));
  return r;
}

// ---------------------------------------------------------------------------
// Kernel 1: blocks 0-11 -> per-(batch,axis) fp64 mean of xyz;
//           blocks 12+  -> float4 zero-fill of sums+cnts (4.26 MB, ~1 us).
// ---------------------------------------------------------------------------
__global__ __launch_bounds__(256) void k_init(
    const float* __restrict__ xyz, float* __restrict__ means,
    float* __restrict__ fill) {
  const int blk = blockIdx.x;
  if (blk >= 12) {
    const int base = (blk - 12) * (256 * 4) + threadIdx.x * 4;
    *(float4*)(fill + base) = make_float4(0.f, 0.f, 0.f, 0.f);
    return;
  }
  __shared__ double red[256];
  const float* p = xyz + blk * N_;
  double s = 0.0;
  for (int i = threadIdx.x; i < N_; i += 256) s += (double)p[i];
  red[threadIdx.x] = s;
  __syncthreads();
  for (int st = 128; st; st >>= 1) {
    if (threadIdx.x < st) red[threadIdx.x] += red[threadIdx.x + st];
    __syncthreads();
  }
  if (threadIdx.x == 0) means[blk] = (float)(red[0] * (1.0 / (double)N_));
}

// ---------------------------------------------------------------------------
// Kernel 2 (round-4 proven): per 64-point tile — transpose x -> xT bf16,
// hproj matvec, pack pts8, voxel scatter via global atomics (coalesced 256B
// bursts). grid = B*N/64, block = 256.
// ---------------------------------------------------------------------------
__global__ __launch_bounds__(256) void k_prep(
    const float* __restrict__ x, const float* __restrict__ xyz,
    const float* __restrict__ pw1, const float* __restrict__ means,
    unsigned short* __restrict__ xT, float* __restrict__ pts,
    float* __restrict__ sums, float* __restrict__ cnts) {
  __shared__ float tile[64 * 65];
  __shared__ float ncs[3][64];
  __shared__ int   flats[64];

  const int t   = threadIdx.x;
  const int blk = blockIdx.x;
  const int b   = blk >> 8;          // 256 tiles per batch
  const int n0  = (blk & 255) << 6;

#pragma unroll
  for (int i = 0; i < 16; ++i) {
    int c = i * 4 + (t >> 6);
    int j = t & 63;
    tile[c * 65 + j] = x[((size_t)(b * C_ + c)) * N_ + n0 + j];
  }
  __syncthreads();

#pragma unroll
  for (int i = 0; i < 16; ++i) {
    int p = i * 4 + (t >> 6);
    int c = t & 63;
    xT[((size_t)(b * N_ + n0 + p)) * C_ + c] = f2bf(tile[c * 65 + p]);
  }

  if (t < 192) {
    int p = t & 63, q = t >> 6;
    float s = 0.f;
#pragma unroll
    for (int c = 0; c < 64; ++c) s = fmaf(pw1[q * 64 + c], tile[c * 65 + p], s);
    size_t pb = ((size_t)(b * N_ + n0 + p)) * 8;
    pts[pb + 3 + q] = s;
    float v = xyz[((size_t)(b * 3 + q)) * N_ + n0 + p];
    pts[pb + q] = v;
    float nc = fminf(fmaxf((v - means[b * 3 + q] + 1.0f) * 8.0f, 0.0f), 15.0f);
    ncs[q][p] = nc;
  } else {
    int p = t & 63;
    size_t pb = ((size_t)(b * N_ + n0 + p)) * 8;
    pts[pb + 6] = 0.f;
    pts[pb + 7] = 0.f;
  }
  __syncthreads();

  if (t < 64) {
    int vx = (int)rintf(ncs[0][t]);
    int vy = (int)rintf(ncs[1][t]);
    int vz = (int)rintf(ncs[2][t]);
    int f = (vx * 16 + vy) * 16 + vz;
    flats[t] = f;
    atomicAdd(&cnts[b * R3_ + f], 1.0f);
  }
  __syncthreads();

  const int w = t >> 6, lane = t & 63;
#pragma unroll
  for (int i = 0; i < 16; ++i) {
    int p = w * 16 + i;
    int f = flats[p];
    atomicAdd(&sums[((size_t)(b * R3_ + f)) * C_ + lane], tile[lane * 65 + p]);
  }
}

// ---------------------------------------------------------------------------
// Kernel 3: 64x64 LDS tile transpose with fused mean-divide:
// vT[b][c][vox] = sums[b][vox][c] / max(cnt,1). Both sides coalesced.
// grid = B*64 = 256 blocks.
// ---------------------------------------------------------------------------
__global__ __launch_bounds__(256) void k_tr(
    const float* __restrict__ sums, const float* __restrict__ cnts,
    float* __restrict__ vT) {
  __shared__ float tile[64 * 65];
  const int t = threadIdx.x;
  const int b = blockIdx.x >> 6;
  const int v0 = (blockIdx.x & 63) << 6;

#pragma unroll
  for (int i = 0; i < 16; ++i) {
    int r = i * 4 + (t >> 6);
    int c = t & 63;
    tile[r * 65 + c] = sums[((size_t)(b * R3_ + v0 + r)) * C_ + c];
  }
  const float rcnt = 1.0f / fmaxf(cnts[b * R3_ + v0 + (t & 63)], 1.0f);
  __syncthreads();
#pragma unroll
  for (int i = 0; i < 16; ++i) {
    int c = i * 4 + (t >> 6);
    int r = t & 63;
    vT[((size_t)(b * C_ + c)) * R3_ + v0 + r] = tile[r * 65 + c] * rcnt;
  }
}

// ---------------------------------------------------------------------------
// Kernel 4: depthwise conv3d x2 with folded bias+BN+LeakyReLU. One block per
// (b,c); input now a CONTIGUOUS 16 KB row of vT (coalesced, independent
// loads — fixes the strided-column latency of the old version).
// ---------------------------------------------------------------------------
__global__ __launch_bounds__(256) void k_conv(
    const float* __restrict__ vT,
    const float* __restrict__ w3d1, const float* __restrict__ b3d1,
    const float* __restrict__ bn1, const float* __restrict__ w3d2,
    const float* __restrict__ b3d2, const float* __restrict__ bn2,
    unsigned short* __restrict__ vox2) {
  __shared__ float va[18 * 18 * 18];
  __shared__ float vb[18 * 18 * 18];
  const int t = threadIdx.x;
  const int b = blockIdx.x >> 6;
  const int c = blockIdx.x & 63;

  float W1[27], W2[27];
#pragma unroll
  for (int i = 0; i < 27; ++i) { W1[i] = w3d1[c * 27 + i]; W2[i] = w3d2[c * 27 + i]; }
  const float s1 = bn1[c] / sqrtf(bn1[192 + c] + 1e-4f);
  const float d1 = (b3d1[c] - bn1[128 + c]) * s1 + bn1[64 + c];
  const float s2 = bn2[c] / sqrtf(bn2[192 + c] + 1e-4f);
  const float d2 = (b3d2[c] - bn2[128 + c]) * s2 + bn2[64 + c];

  for (int i = t; i < 18 * 18 * 18; i += 256) { va[i] = 0.f; vb[i] = 0.f; }
  const float* __restrict__ vrow = vT + ((size_t)(b * C_ + c)) * R3_;
  __syncthreads();

#pragma unroll
  for (int i = 0; i < 16; ++i) {
    int vox = t + i * 256;
    int z = vox & 15, y = (vox >> 4) & 15, xx = vox >> 8;
    va[((xx + 1) * 18 + (y + 1)) * 18 + (z + 1)] = vrow[vox];
  }
  __syncthreads();

#pragma unroll
  for (int i = 0; i < 16; ++i) {
    int vox = t + i * 256;
    int z = vox & 15, y = (vox >> 4) & 15, xx = vox >> 8;
    int base = ((xx + 1) * 18 + (y + 1)) * 18 + (z + 1);
    float acc = 0.f;
#pragma unroll
    for (int dx = -1; dx <= 1; ++dx)
#pragma unroll
      for (int dy = -1; dy <= 1; ++dy)
#pragma unroll
        for (int dz = -1; dz <= 1; ++dz)
          acc = fmaf(W1[((dx + 1) * 3 + (dy + 1)) * 3 + (dz + 1)],
                     va[base + dx * 324 + dy * 18 + dz], acc);
    float tt = acc * s1 + d1;
    vb[base] = tt > 0.f ? tt : 0.1f * tt;
  }
  __syncthreads();

#pragma unroll
  for (int i = 0; i < 16; ++i) {
    int vox = t + i * 256;
    int z = vox & 15, y = (vox >> 4) & 15, xx = vox >> 8;
    int base = ((xx + 1) * 18 + (y + 1)) * 18 + (z + 1);
    float acc = 0.f;
#pragma unroll
    for (int dx = -1; dx <= 1; ++dx)
#pragma unroll
      for (int dy = -1; dy <= 1; ++dy)
#pragma unroll
        for (int dz = -1; dz <= 1; ++dz)
          acc = fmaf(W2[((dx + 1) * 3 + (dy + 1)) * 3 + (dz + 1)],
                     vb[base + dx * 324 + dy * 18 + dz], acc);
    float tt = acc * s2 + d2;
    vox2[((size_t)(b * R3_ + vox)) * C_ + c] = f2bf(tt > 0.f ? tt : 0.1f * tt);
  }
}

// ---------------------------------------------------------------------------
// Kernel 5: fused trilinear devoxelize + point branch + add.
//  A) 512 (p,k) pairs: 6 distinct weights once per pair, bf16-packed in LDS.
//  B) wave=point, lane=channel: ALL 24 gathers per point issued back-to-back
//     (8 vox + 16 xj) before any use -> deep vmcnt pipeline; 1-op per-lane
//     shift extracts the packed weight. grid = B*N/32. XCD batch swizzle.
// ---------------------------------------------------------------------------
__global__ __launch_bounds__(256, 8) void k_final(
    const unsigned short* __restrict__ xT, const float* __restrict__ pts,
    const unsigned short* __restrict__ vox2, const int* __restrict__ idx,
    const float* __restrict__ means, const float* __restrict__ pbn,
    const float* __restrict__ pw2, const float* __restrict__ ptbn,
    float* __restrict__ out) {
  __shared__ unsigned w6[3][513];   // [dword][pair] packed 2xbf16 (513: bank-skew)
  __shared__ int      jarr[512];
  __shared__ unsigned dv[32][8];    // (corner voxidx << 16) | bf16(weight)
  __shared__ float    outT[64 * 33];

  const int t = threadIdx.x;
  const int blk = blockIdx.x;
  const int xcd = blk & 7;
  const int b = xcd >> 1;                          // XCD pair -> batch
  const int t32 = ((blk >> 3) << 1) | (xcd & 1);   // tile in [0,512)
  const int n0 = t32 * 32;

  const float psc0 = pbn[0] * rsqrtf(pbn[9]  + 1e-5f);
  const float psc1 = pbn[1] * rsqrtf(pbn[10] + 1e-5f);
  const float psc2 = pbn[2] * rsqrtf(pbn[11] + 1e-5f);
  const float pof0 = pbn[3] - pbn[6] * psc0;
  const float pof1 = pbn[4] - pbn[7] * psc1;
  const float pof2 = pbn[5] - pbn[8] * psc2;
  float W2r[9];
#pragma unroll
  for (int i = 0; i < 9; ++i) W2r[i] = pw2[i];

  const float* __restrict__ ptsb = pts + (size_t)b * N_ * 8;

  // ---------------- phase A: 512 pairs, 2 per thread ----------------
#pragma unroll
  for (int rep = 0; rep < 2; ++rep) {
    const int q = t + rep * 256;        // pair id = p*16 + k
    const int p = q >> 4;
    const int n = n0 + p;
    const int j = idx[(size_t)b * N_ * K_ + (size_t)n0 * K_ + q];
    jarr[q] = j;
    const float* qr = ptsb + (size_t)j * 8;
    float4 qa = *(const float4*)qr;
    float4 qb = *(const float4*)(qr + 4);
    const float* ir = ptsb + (size_t)n * 8;
    float4 pa = *(const float4*)ir;
    float4 pb = *(const float4*)(ir + 4);
    float d0 = qa.x - pa.x, d1 = qa.y - pa.y, d2 = qa.z - pa.z;
    float c0 = pof0 - psc0 * pa.w;
    float c1 = pof1 - psc1 * pb.x;
    float c2 = pof2 - psc2 * pb.y;
    float h0 = fmaxf(fmaf(qa.w, psc0, c0), 0.f);
    float h1 = fmaxf(fmaf(qb.x, psc1, c1), 0.f);
    float h2 = fmaxf(fmaf(qb.y, psc2, c2), 0.f);
    float e0 = fmaf(W2r[0], h0, fmaf(W2r[1], h1, W2r[2] * h2));
    float e1 = fmaf(W2r[3], h0, fmaf(W2r[4], h1, W2r[5] * h2));
    float e2 = fmaf(W2r[6], h0, fmaf(W2r[7], h1, W2r[8] * h2));
    w6[0][q] = cvtpk_bf16(d0, d1);
    w6[1][q] = cvtpk_bf16(d2, e0);
    w6[2][q] = cvtpk_bf16(e1, e2);
  }

  if (t < 32) {
    const int n = n0 + t;
    const float* ir = ptsb + (size_t)n * 8;
    float x0 = ir[0], x1 = ir[1], x2 = ir[2];
    float nc0 = fminf(fmaxf((x0 - means[b * 3 + 0] + 1.0f) * 8.0f, 0.0f), 15.0f);
    float nc1 = fminf(fmaxf((x1 - means[b * 3 + 1] + 1.0f) * 8.0f, 0.0f), 15.0f);
    float nc2 = fminf(fmaxf((x2 - means[b * 3 + 2] + 1.0f) * 8.0f, 0.0f), 15.0f);
    int lx = (int)nc0, ly = (int)nc1, lz = (int)nc2;
    float fx = nc0 - (float)lx, fy = nc1 - (float)ly, fz = nc2 - (float)lz;
    int hx = lx < 15 ? lx + 1 : 15;
    int hy = ly < 15 ? ly + 1 : 15;
    int hz = lz < 15 ? lz + 1 : 15;
    float wx[2] = {1.f - fx, fx};
    float wy[2] = {1.f - fy, fy};
    float wz[2] = {1.f - fz, fz};
    int xi[2] = {lx, hx}, yi[2] = {ly, hy}, zi[2] = {lz, hz};
#pragma unroll
    for (int c8 = 0; c8 < 8; ++c8) {
      int dx = c8 >> 2, dy = (c8 >> 1) & 1, dz = c8 & 1;
      int flat = (xi[dx] * 16 + yi[dy]) * 16 + zi[dz];
      float wt = wx[dx] * wy[dy] * wz[dz];
      dv[t][c8] = ((unsigned)flat << 16) | (unsigned)f2bf(wt);
    }
  }
  __syncthreads();

  // ---------------- phase B: wave = point, lane = channel ----------------
  const int w = t >> 6, lane = t & 63;
  // groups: 0-9 d0 | 10-19 d1 | 20-29 d2 | 30-39 e0 | 40-49 e1 | 50-63 e2
  const int widx = lane < 20 ? 0 : lane < 40 ? 1 : 2;
  const bool hi = (lane >= 10 && lane < 20) || (lane >= 30 && lane < 40) || (lane >= 50);
  const unsigned shl = hi ? 0u : 16u;   // hi lanes keep low-mantissa garbage (<=2^-9 rel)
  const float ts = ptbn[lane] * rsqrtf(ptbn[192 + lane] + 1e-5f);
  const float td = ptbn[64 + lane] - ptbn[128 + lane] * ts;
  const unsigned short* __restrict__ xTb = xT + (size_t)b * N_ * C_;
  const unsigned short* __restrict__ voxb = vox2 + (size_t)b * R3_ * C_;

#pragma unroll
  for (int i = 0; i < 8; ++i) {
    const int p = i * 4 + w;
    const int pq = p * 16;

    // issue ALL gathers for this point back-to-back (deep vmcnt pipeline)
    unsigned short vxv[8];
#pragma unroll
    for (int c8 = 0; c8 < 8; ++c8)
      vxv[c8] = voxb[(size_t)(dv[p][c8] >> 16) * C_ + lane];
    unsigned short xjv[16];
#pragma unroll
    for (int k = 0; k < 16; ++k)
      xjv[k] = xTb[(size_t)jarr[pq + k] * C_ + lane];

    // devox (consumes vxv first — xj loads still in flight)
    float acc = 0.f;
#pragma unroll
    for (int c8 = 0; c8 < 8; ++c8)
      acc = fmaf(__uint_as_float(dv[p][c8] << 16), bf2f(vxv[c8]), acc);

    // neighbor max-pool (relu folded into pm=0 init)
    float pm = 0.f;
#pragma unroll
    for (int k = 0; k < 16; ++k) {
      float wf = __uint_as_float(w6[widx][pq + k] << shl);
      pm = fmaxf(pm, fmaf(bf2f(xjv[k]) * wf, ts, td));
    }

    outT[lane * 33 + p] = acc + pm;
  }
  __syncthreads();

#pragma unroll
  for (int i = 0; i < 8; ++i) {
    int c = i * 8 + (t >> 5);
    int col = t & 31;
    out[((size_t)(b * C_ + c)) * N_ + n0 + col] = outT[c * 33 + col];
  }
}

// ---------------------------------------------------------------------------
extern "C" void kernel_launch(void* const* d_in, const int* in_sizes, int n_in,
                              void* d_out, int out_size, void* d_ws, size_t ws_size,
                              hipStream_t stream) {
  const float* x     = (const float*)d_in[0];
  const float* xyz   = (const float*)d_in[1];
  const int*   idx   = (const int*)  d_in[2];
  const float* w3d1  = (const float*)d_in[3];
  const float* b3d1  = (const float*)d_in[4];
  const float* bn3d1 = (const float*)d_in[5];
  const float* w3d2  = (const float*)d_in[6];
  const float* b3d2  = (const float*)d_in[7];
  const float* bn3d2 = (const float*)d_in[8];
  const float* pw1   = (const float*)d_in[9];
  const float* pbn   = (const float*)d_in[10];
  const float* pw2   = (const float*)d_in[11];
  const float* ptbn  = (const float*)d_in[12];
  float* out = (float*)d_out;
  float* ws  = (float*)d_ws;

  k_init<<<dim3(12 + FILL_BLOCKS), dim3(256), 0, stream>>>(
      xyz, ws + OFF_MEANS, ws + OFF_SUMS);
  k_prep<<<dim3(B_ * N_ / 64), dim3(256), 0, stream>>>(
      x, xyz, pw1, ws + OFF_MEANS, (unsigned short*)(ws + OFF_XT), ws + OFF_PTS,
      ws + OFF_SUMS, ws + OFF_CNTS);
  k_tr<<<dim3(B_ * 64), dim3(256), 0, stream>>>(
      ws + OFF_SUMS, ws + OFF_CNTS, ws + OFF_VT);
  k_conv<<<dim3(B_ * C_), dim3(256), 0, stream>>>(
      ws + OFF_VT, w3d1, b3d1, bn3d1, w3d2, b3d2, bn3d2,
      (unsigned short*)(ws + OFF_VOX2));
  k_final<<<dim3(B_ * N_ / 32), dim3(256), 0, stream>>>(
      (const unsigned short*)(ws + OFF_XT), ws + OFF_PTS,
      (const unsigned short*)(ws + OFF_VOX2), idx, ws + OFF_MEANS,
      pbn, pw2, ptbn, out);
}